// Round 4
// baseline (202.657 us; speedup 1.0000x reference)
//
#include <hip/hip_runtime.h>
#include <cmath>

// Problem: x [8, 512, 32, 32] fp32. GroupNorm(32) -> QKV 1x1 -> attention -> proj 1x1 -> +x
constexpr int Bsz = 8, Cch = 512, NPIX = 1024;
constexpr int NG = 32, CPG = 16;

typedef __attribute__((ext_vector_type(4))) float f32x4;
typedef __attribute__((ext_vector_type(8))) short s16x8;

#define GLOBAL_AS __attribute__((address_space(1)))
#define LDS_AS __attribute__((address_space(3)))

__device__ inline short f2bf(float f) {  // RNE fp32 -> bf16
  union { float f; unsigned u; } c = {f};
  unsigned r = (c.u + 0x7fffu + ((c.u >> 16) & 1u)) >> 16;
  return (short)r;
}

__device__ inline float wave_reduce_sum(float v) {
#pragma unroll
  for (int off = 32; off > 0; off >>= 1) v += __shfl_xor(v, off, 64);
  return v;
}
__device__ inline float wave_reduce_max(float v) {
#pragma unroll
  for (int off = 32; off > 0; off >>= 1) v = fmaxf(v, __shfl_xor(v, off, 64));
  return v;
}

// ---------------- fp32 -> bf16 weight conversion (both weights, one dispatch) ----
__global__ __launch_bounds__(256) void cvt_kernel(const float* __restrict__ in1,
                                                  short* __restrict__ out1, int n1,
                                                  const float* __restrict__ in2,
                                                  short* __restrict__ out2, int n2) {
  const int i = (blockIdx.x * 256 + threadIdx.x) * 4;
  const float* in = in1;
  short* out = out1;
  int j = i;
  if (i >= n1) { in = in2; out = out2; j = i - n1; }
  if (j + 3 < (i >= n1 ? n2 : n1)) {
    float4 v = *(const float4*)(in + j);
    short o[4] = {f2bf(v.x), f2bf(v.y), f2bf(v.z), f2bf(v.w)};
    *(uint2*)(out + j) = *(const uint2*)o;
  }
}

// ---------------- GroupNorm, writes TRANSPOSED bf16 xnt[b][pix][c] ----------------
__global__ __launch_bounds__(256) void gn_kernel(
    const float* __restrict__ x, const float* __restrict__ w,
    const float* __restrict__ bb, short* __restrict__ xnt) {
  __shared__ float sm[8];
  const int bg = blockIdx.x, b = bg >> 5, g = bg & 31;
  const float* xp = x + ((size_t)(b * Cch + g * CPG)) * NPIX;
  float s = 0.f, ss = 0.f;
  for (int i = threadIdx.x * 4; i < CPG * NPIX; i += 1024) {
    float4 v = *(const float4*)(xp + i);
    s += v.x + v.y + v.z + v.w;
    ss += v.x * v.x + v.y * v.y + v.z * v.z + v.w * v.w;
  }
  s = wave_reduce_sum(s);
  ss = wave_reduce_sum(ss);
  const int wv = threadIdx.x >> 6;
  if ((threadIdx.x & 63) == 0) { sm[wv] = s; sm[4 + wv] = ss; }
  __syncthreads();
  const float tsum = sm[0] + sm[1] + sm[2] + sm[3];
  const float tsq = sm[4] + sm[5] + sm[6] + sm[7];
  const float inv_n = 1.0f / (CPG * NPIX);
  const float mean = tsum * inv_n;
  const float rstd = rsqrtf(tsq * inv_n - mean * mean + 1e-5f);
  float wc[CPG], bc[CPG];
#pragma unroll
  for (int c = 0; c < CPG; ++c) {
    wc[c] = w[g * CPG + c] * rstd;
    bc[c] = bb[g * CPG + c] - mean * wc[c];
  }
  for (int p = threadIdx.x; p < NPIX; p += 256) {
    short ov[CPG];
#pragma unroll
    for (int c = 0; c < CPG; ++c)
      ov[c] = f2bf(xp[(size_t)c * NPIX + p] * wc[c] + bc[c]);
    short* op = xnt + ((size_t)(b * NPIX + p)) * Cch + g * CPG;
    *(uint4*)op = *(const uint4*)&ov[0];
    *(uint4*)(op + 8) = *(const uint4*)&ov[8];
  }
}

// ---------------- bf16 MFMA GEMM: C[m][n] = sum_k A[m][k]*B[n][k] ----------------
// Both operands row-major with k contiguous ("TN"). BM x BN tile, BK=64,
// 256 threads = 4 waves in a 2x2 grid; wave tile (BM/2)x(BN/2) =
// (FM x FN) mfma_f32_16x16x32_bf16 tiles, 2 k-chunks per iter.
// LDS fragment-ordered: staging chunk s -> row=(s>>7)*16+(s&15), q=(s>>4)&7,
// lds addr = s*8 shorts; MFMA fragment (mtile i, kchunk c) reads
// mtile_base + i*1024 + c*512 + lane*8 — pure ds_read_b128, conflict-free.
// EPI 0: qkv split  -> m<1024: bf16 Cq[n*ldc+m] (+bias); else bf16 C2[(m-1024)*ldc+n] (+bias)
// EPI 1: fp32 C[m*ldc+n] = acc*alpha
// EPI 2: bf16 C[m*ldc+n] = acc
// EPI 3: fp32 C[m*ldc+n] = acc + bias[m] + resid[m*ldc+n]
template <int BM, int BN, int EPI>
__global__ __launch_bounds__(256) void mfma_gemm(
    const short* __restrict__ A, const short* __restrict__ B, int K, int lda,
    int ldb, long sA, long sB, const float* __restrict__ bias, float alpha,
    void* __restrict__ Cp, long sC, int ldc, void* __restrict__ C2p, long sC2,
    const float* __restrict__ resid, long sR) {
  constexpr int FM = BM / 32, FN = BN / 32;   // frag tiles per wave
  constexpr int NA = BM / 32, NB = BN / 32;   // staging iters (256 thr x 16B, BK=64)
  __shared__ __align__(16) short Asl[BM * 64];  // fragment-ordered
  __shared__ __align__(16) short Bsl[BN * 64];
  const int t = threadIdx.x;
  const int lane = t & 63, wave = t >> 6;
  const int bz = blockIdx.z;
  const int m0 = blockIdx.y * BM, n0 = blockIdx.x * BN;
  A += sA * bz;
  B += sB * bz;

  // staging: chunk s covers row = (s>>7)*16 + (s&15), k-oct q = (s>>4)&7
  const short* ga[NA];
  const short* gb[NB];
  short* la[NA];
  short* lb[NB];
#pragma unroll
  for (int i = 0; i < NA; ++i) {
    const int s = i * 256 + t;
    const int row = ((s >> 7) * 16) + (s & 15);
    const int q = (s >> 4) & 7;
    ga[i] = A + (size_t)(m0 + row) * lda + q * 8;
    la[i] = Asl + s * 8;
  }
#pragma unroll
  for (int i = 0; i < NB; ++i) {
    const int s = i * 256 + t;
    const int row = ((s >> 7) * 16) + (s & 15);
    const int q = (s >> 4) & 7;
    gb[i] = B + (size_t)(n0 + row) * ldb + q * 8;
    lb[i] = Bsl + s * 8;
  }

  f32x4 acc[FM][FN] = {};
  const int wm = wave & 1, wn = wave >> 1;

  for (int k0 = 0; k0 < K; k0 += 64) {
#pragma unroll
    for (int i = 0; i < NA; ++i) {
      __builtin_amdgcn_global_load_lds((const GLOBAL_AS void*)ga[i],
                                       (LDS_AS void*)la[i], 16, 0, 0);
      ga[i] += 64;
    }
#pragma unroll
    for (int i = 0; i < NB; ++i) {
      __builtin_amdgcn_global_load_lds((const GLOBAL_AS void*)gb[i],
                                       (LDS_AS void*)lb[i], 16, 0, 0);
      gb[i] += 64;
    }
    __syncthreads();
#pragma unroll
    for (int c = 0; c < 2; ++c) {
      s16x8 af[FM], bf[FN];
#pragma unroll
      for (int i = 0; i < FM; ++i)
        af[i] = *(const s16x8*)(Asl + (wm * FM + i) * 1024 + c * 512 + lane * 8);
#pragma unroll
      for (int i = 0; i < FN; ++i)
        bf[i] = *(const s16x8*)(Bsl + (wn * FN + i) * 1024 + c * 512 + lane * 8);
#pragma unroll
      for (int im = 0; im < FM; ++im)
#pragma unroll
        for (int in = 0; in < FN; ++in)
          acc[im][in] = __builtin_amdgcn_mfma_f32_16x16x32_bf16(
              af[im], bf[in], acc[im][in], 0, 0, 0);
    }
    __syncthreads();
  }

  // epilogue. C/D frag: row m = quad*4+r, col n = lane&15 (within 16x16 tile)
  const int quad = lane >> 4, nn = lane & 15;
#pragma unroll
  for (int im = 0; im < FM; ++im) {
#pragma unroll
    for (int in = 0; in < FN; ++in) {
      const int m = m0 + (wm * FM + im) * 16 + quad * 4;
      const int n = n0 + (wn * FN + in) * 16 + nn;
      if (EPI == 0) {
        if (m0 < 1024) {
          short* Cq = (short*)Cp + sC * bz;
          short o[4];
#pragma unroll
          for (int r = 0; r < 4; ++r) o[r] = f2bf(acc[im][in][r] + bias[m + r]);
          *(uint2*)(Cq + (size_t)n * ldc + m) = *(const uint2*)o;
        } else {
          short* Cv = (short*)C2p + sC2 * bz;
#pragma unroll
          for (int r = 0; r < 4; ++r)
            Cv[(size_t)(m - 1024 + r) * ldc + n] =
                f2bf(acc[im][in][r] + bias[m + r]);
        }
      } else if (EPI == 1) {
        float* Cf = (float*)Cp + sC * bz;
#pragma unroll
        for (int r = 0; r < 4; ++r)
          Cf[(size_t)(m + r) * ldc + n] = acc[im][in][r] * alpha;
      } else if (EPI == 2) {
        short* Cs = (short*)Cp + sC * bz;
#pragma unroll
        for (int r = 0; r < 4; ++r)
          Cs[(size_t)(m + r) * ldc + n] = f2bf(acc[im][in][r]);
      } else {
        float* Cf = (float*)Cp + sC * bz;
        const float* R = resid + sR * bz;
#pragma unroll
        for (int r = 0; r < 4; ++r)
          Cf[(size_t)(m + r) * ldc + n] =
              acc[im][in][r] + bias[m + r] + R[(size_t)(m + r) * ldc + n];
      }
    }
  }
}

// ---------------- row softmax over 1024, fp32 in -> bf16 out ----------------
__global__ __launch_bounds__(256) void softmax_kernel(const float* __restrict__ S,
                                                      short* __restrict__ P) {
  __shared__ float sm[8];
  const float* p = S + (size_t)blockIdx.x * 1024;
  const int t = threadIdx.x;
  float4 v = ((const float4*)p)[t];
  float mx = fmaxf(fmaxf(v.x, v.y), fmaxf(v.z, v.w));
  mx = wave_reduce_max(mx);
  if ((t & 63) == 0) sm[t >> 6] = mx;
  __syncthreads();
  mx = fmaxf(fmaxf(sm[0], sm[1]), fmaxf(sm[2], sm[3]));
  v.x = __expf(v.x - mx);
  v.y = __expf(v.y - mx);
  v.z = __expf(v.z - mx);
  v.w = __expf(v.w - mx);
  float s = v.x + v.y + v.z + v.w;
  s = wave_reduce_sum(s);
  if ((t & 63) == 0) sm[4 + (t >> 6)] = s;
  __syncthreads();
  const float inv = 1.0f / (sm[4] + sm[5] + sm[6] + sm[7]);
  short o[4] = {f2bf(v.x * inv), f2bf(v.y * inv), f2bf(v.z * inv),
                f2bf(v.w * inv)};
  *(uint2*)(P + (size_t)blockIdx.x * 1024 + t * 4) = *(const uint2*)o;
}

// ---------------- launch ----------------
extern "C" void kernel_launch(void* const* d_in, const int* in_sizes, int n_in,
                              void* d_out, int out_size, void* d_ws,
                              size_t ws_size, hipStream_t stream) {
  const float* x = (const float*)d_in[0];
  const float* gnw = (const float*)d_in[1];
  const float* gnb = (const float*)d_in[2];
  const float* qkvw = (const float*)d_in[3];   // [1536, 512]
  const float* qkvb = (const float*)d_in[4];   // [1536]
  const float* projw = (const float*)d_in[5];  // [512, 512]
  const float* projb = (const float*)d_in[6];  // [512]
  float* out = (float*)d_out;

  char* ws = (char*)d_ws;
  short* xnt = (short*)ws;                       //  8 MiB [b][1024 pix][512 c] bf16
  short* qkt = (short*)(ws + (8ull << 20));      // 16 MiB [b][1024 pix][1024: Q|K] bf16
  short* vbuf = (short*)(ws + (24ull << 20));    //  8 MiB [b][512 c][1024 pix] bf16
  float* Sbuf = (float*)(ws + (32ull << 20));    // 32 MiB [b][1024][1024] fp32
  short* Pbuf = (short*)(ws + (64ull << 20));    // 16 MiB [b][1024][1024] bf16
  short* Ot = (short*)(ws + (80ull << 20));      //  8 MiB [b][1024 pix][512 c] bf16
  short* wq = (short*)(ws + (88ull << 20));      // 1.5 MiB
  short* wp = (short*)(ws + (89ull << 20) + (512ull << 10));  // 0.5 MiB

  // weights -> bf16 (one dispatch covers both)
  cvt_kernel<<<1024, 256, 0, stream>>>(qkvw, wq, 1536 * 512, projw, wp,
                                       512 * 512);

  // GroupNorm -> xnt (transposed bf16)
  gn_kernel<<<Bsz * NG, 256, 0, stream>>>(x, gnw, gnb, xnt);

  // QKV: C[m][n] = sum_k wq[m][k] xnt[n][k]; M=1536 N=1024 K=512
  //   m<1024 -> qkt[n][m]; m>=1024 -> v[m-1024][n]
  mfma_gemm<128, 128, 0><<<dim3(8, 12, Bsz), 256, 0, stream>>>(
      wq, xnt, 512, 512, 512, 0L, 1024L * 512, qkvb, 1.0f, qkt, 1024L * 1024,
      1024, vbuf, 512L * 1024, nullptr, 0L);

  // S[i][j] = scale * sum_k Q[i][k] K[j][k]; M=N=1024 K=512
  const float scale = 1.0f / sqrtf(512.0f);
  mfma_gemm<128, 128, 1><<<dim3(8, 8, Bsz), 256, 0, stream>>>(
      qkt, qkt + 512, 512, 1024, 1024, 1024L * 1024, 1024L * 1024, nullptr,
      scale, Sbuf, 1024L * 1024, 1024, nullptr, 0L, nullptr, 0L);

  // softmax rows -> P bf16
  softmax_kernel<<<Bsz * 1024, 256, 0, stream>>>(Sbuf, Pbuf);

  // Ot[i][c] = sum_j P[i][j] V[c][j]; M=1024 N=512 K=1024  (128x64 -> 512 blocks)
  mfma_gemm<128, 64, 2><<<dim3(8, 8, Bsz), 256, 0, stream>>>(
      Pbuf, vbuf, 1024, 1024, 1024, 1024L * 1024, 512L * 1024, nullptr, 1.0f,
      Ot, 1024L * 512, 512, nullptr, 0L, nullptr, 0L);

  // out[o][i] = sum_c wp[o][c] Ot[i][c] + projb[o] + x[o][i]; M=512 N=1024 K=512
  // (64x128 -> 512 blocks)
  mfma_gemm<64, 128, 3><<<dim3(8, 8, Bsz), 256, 0, stream>>>(
      wp, Ot, 512, 512, 512, 0L, 1024L * 512, projb, 1.0f, out, 512L * 1024,
      1024, nullptr, 0L, x, 512L * 1024);
}